// Round 12
// baseline (327.241 us; speedup 1.0000x reference)
//
#include <hip/hip_runtime.h>
#include <hip/hip_bf16.h>

// QuantizedLinearINT4: out = x @ dequant(W).T + bias
// M=8192, N=OUT=4096, K=IN=4096.
// Round-12: round-4 proven schedule (256x256, BK=64, 512 thr, 2 phases/K-tile,
// counted vmcnt(4), XCD swizzle, setprio) with v_mfma_f32_32x32x16_bf16
// (m119: 2495 TF vs 2176 for 16x16 -> -13% MFMA cycles, half the inst count)
// and a fully LINEAR LDS tile layout: granule order [t32][kk][kh][row]x16B so
// every fragment is one ds_read_b128 with the wave reading 1024 contiguous
// bytes (conflict-free by construction; no swizzle on either side).
// Fragment layout: A/B row=lane&31, k0=(lane>>5)*8 (generalizes the verified
// 16x16x32 pattern); C/D col=lane&31, row=(reg&3)+8*(reg>>2)+4*(lane>>5).

typedef __bf16 bf16;
typedef __attribute__((ext_vector_type(8))) __bf16 bf16x8;
typedef __attribute__((ext_vector_type(4))) float f32x4;
typedef __attribute__((ext_vector_type(16))) float f32x16;
typedef __attribute__((ext_vector_type(4))) unsigned int u32x4;

#define OUT_DIM 4096
#define IN_DIM  4096
#define M_DIM   8192

// ---------- Pass 1: dequant int4 -> bf16 W[OUT][IN] ----------
__global__ __launch_bounds__(256) void dequant_w_kernel(
    const int* __restrict__ wp, const float* __restrict__ scale,
    const float* __restrict__ zp, bf16* __restrict__ W)
{
  const int t = blockIdx.x * 256 + threadIdx.x;
  const long j = (long)t * 8;
  const int o = (int)(j >> 12);
  const float s = scale[o];
  const float zs = zp[o] * s;
  const int4 p = *(const int4*)(wp + (long)t * 4);
  const int v[4] = {p.x, p.y, p.z, p.w};
  union { bf16 h[8]; u32x4 u; } r;
#pragma unroll
  for (int q = 0; q < 4; ++q) {
    r.h[2*q]   = (bf16)((float)(v[q] & 15) * s - zs);
    r.h[2*q+1] = (bf16)((float)((v[q] >> 4) & 15) * s - zs);
  }
  *(u32x4*)(W + j) = r.u;
}

// ---------- Pass 2: cast x f32 -> bf16 ----------
__global__ __launch_bounds__(256) void cvt_x_kernel(
    const float* __restrict__ x, bf16* __restrict__ xb)
{
  const long t = (long)blockIdx.x * 256 + threadIdx.x;
  const long i = t * 8;
  const f32x4 a = *(const f32x4*)(x + i);
  const f32x4 b = *(const f32x4*)(x + i + 4);
  union { bf16 h[8]; u32x4 u; } r;
#pragma unroll
  for (int q = 0; q < 4; ++q) { r.h[q] = (bf16)a[q]; r.h[4+q] = (bf16)b[q]; }
  *(u32x4*)(xb + i) = r.u;
}

// ---------- Pass 3: 256x256 GEMM-BT, 32x32x16 MFMA, fused bias ----------
// 512 thr = 8 waves (2M x 4N); per wave 128x64 out = 4 Mtiles x 2 Ntiles of
// 32x32 (acc[4][2] f32x16).  LDS per (buf,ks): A 16 KB, B 16 KB, granule
// g = t32*128 + kk*64 + kh*32 + row; byte = g*16 holds rows' bf16[8] at
// k = kk*16 + kh*8.  Total 128 KiB.
// Phase (2/K-tile): vmcnt(4) -> barrier -> 4 B + 8 A ds_read_b128 (linear)
// -> stage next group (4 gload_lds x 16B) -> 16 MFMA.
__global__ __launch_bounds__(512, 2) void gemm_bt_bias_kernel(
    const bf16* __restrict__ A, const bf16* __restrict__ B,
    const float* __restrict__ bias, float* __restrict__ C)
{
  const int N = OUT_DIM, K = IN_DIM;
  const int NT = IN_DIM / 64;            // 64 K-tiles

  __shared__ char smA[2][2][16384];      // 64 KiB
  __shared__ char smB[2][2][16384];      // 64 KiB

  // T1: XCD-aware bijective swizzle (512 blocks, 512 % 8 == 0)
  const int bid = blockIdx.x;
  const int swz = (bid & 7) * (512 / 8) + (bid >> 3);
  const int bm = swz >> 4;               // 32 row-tiles
  const int bn = swz & 15;               // 16 col-tiles

  const int tid  = threadIdx.x;
  const int lane = tid & 63;
  const int wave = tid >> 6;
  const int wr = wave >> 2;              // 0..1 -> 128-row strip
  const int wc = wave & 3;               // 0..3 -> 64-col strip

  const long row0 = (long)bm * 256;
  const long col0 = (long)bn * 256;

  // --- staging source decode: thread tid covers granule g=tid (chunk0) and
  // g=512+tid (chunk1): t32=g>>7, kk=(g>>6)&1, kh=(g>>5)&1, row=g&31 ---
  const int arow = (tid >> 7) * 32 + (tid & 31);           // chunk0 row (0..127)
  const int kadj = ((tid >> 6) & 1) * 16 + ((tid >> 5) & 1) * 8;
  const bf16* aP0 = A + (row0 + arow) * (long)K + kadj;
  const bf16* aP1 = aP0 + 128 * (long)K;                   // chunk1: t32 += 4
  const bf16* bP0 = B + (col0 + arow) * (long)K + kadj;
  const bf16* bP1 = bP0 + 128 * (long)K;
  const int LA = tid * 16;

#define GL(P, D) __builtin_amdgcn_global_load_lds(                              \
      (const __attribute__((address_space(1))) void*)(P),                       \
      (__attribute__((address_space(3))) void*)(D), 16, 0, 0)

#define STAGE_G(BUF, KS, KOFF) do {                                             \
    char* Ah = &smA[BUF][KS][0];                                                \
    char* Bh = &smB[BUF][KS][0];                                                \
    GL(aP0 + (KOFF), Ah + LA);                                                  \
    GL(aP1 + (KOFF), Ah + 8192 + LA);                                           \
    GL(bP0 + (KOFF), Bh + LA);                                                  \
    GL(bP1 + (KOFF), Bh + 8192 + LA);                                           \
  } while (0)

  // --- ds_read per-lane constant: frag(t32,kk) at t32*2048 + kk*1024 + laneoff
  const int laneoff = ((lane >> 5) << 9) + ((lane & 31) << 4);
  const int waB = wr * 4 * 2048;         // A: wave's first Mtile byte offset
  const int wbB = wc * 2 * 2048;         // B: wave's first Ntile byte offset

  f32x16 acc[4][2] = {};

#define PHASE(BUF, KS, STAGE_STMT, VM_STMT) do {                                \
    VM_STMT;                                                                    \
    __builtin_amdgcn_s_barrier();                                               \
    asm volatile("" ::: "memory");  /* keep LDS reads below the barrier */      \
    const char* Ab = &smA[BUF][KS][0];                                          \
    const char* Bb = &smB[BUF][KS][0];                                          \
    bf16x8 fb[2][2], fa[4][2];                                                  \
    _Pragma("unroll")                                                           \
    for (int n = 0; n < 2; ++n)                                                 \
      _Pragma("unroll")                                                         \
      for (int kk = 0; kk < 2; ++kk)                                            \
        fb[n][kk] = *(const bf16x8*)(Bb + wbB + n * 2048 + kk * 1024 + laneoff);\
    _Pragma("unroll")                                                           \
    for (int m = 0; m < 4; ++m)                                                 \
      _Pragma("unroll")                                                         \
      for (int kk = 0; kk < 2; ++kk)                                            \
        fa[m][kk] = *(const bf16x8*)(Ab + waB + m * 2048 + kk * 1024 + laneoff);\
    STAGE_STMT;                                                                 \
    __builtin_amdgcn_s_setprio(1);                                              \
    _Pragma("unroll")                                                           \
    for (int kk = 0; kk < 2; ++kk)                                              \
      _Pragma("unroll")                                                         \
      for (int m = 0; m < 4; ++m)                                               \
        _Pragma("unroll")                                                       \
        for (int n = 0; n < 2; ++n)                                             \
          acc[m][n] = __builtin_amdgcn_mfma_f32_32x32x16_bf16(                  \
              fa[m][kk], fb[n][kk], acc[m][n], 0, 0, 0);                        \
    __builtin_amdgcn_s_setprio(0);                                              \
  } while (0)

  // Prologue: tile 0, both ks groups (8 loads in flight)
  STAGE_G(0, 0, 0);
  STAGE_G(0, 1, 32);

  for (int T = 0; T < NT; ++T) {
    const int buf = T & 1;
    const int nbuf = buf ^ 1;
    const int nko = (T + 1) * 64;
    const bool st = (T + 1 < NT);

    PHASE(buf, 0,
          { if (st) STAGE_G(nbuf, 0, nko); },
          { asm volatile("s_waitcnt vmcnt(4)" ::: "memory"); });
    PHASE(buf, 1,
          { if (st) STAGE_G(nbuf, 1, nko + 32); },
          { if (T == NT - 1) asm volatile("s_waitcnt vmcnt(0)" ::: "memory");
            else             asm volatile("s_waitcnt vmcnt(4)" ::: "memory"); });
  }

  // Epilogue: 32x32 C/D layout col=lane&31, row=(reg&3)+8*(reg>>2)+4*(lane>>5)
  const int l31 = lane & 31;
  const int hi4 = (lane >> 5) * 4;
  const long cr0 = row0 + wr * 128 + hi4;
  float bv[2];
#pragma unroll
  for (int n = 0; n < 2; ++n) bv[n] = bias[col0 + wc * 64 + n * 32 + l31];
#pragma unroll
  for (int n = 0; n < 2; ++n) {
    const long gc = col0 + wc * 64 + n * 32 + l31;
#pragma unroll
    for (int m = 0; m < 4; ++m) {
#pragma unroll
      for (int q = 0; q < 4; ++q) {
        float* cp = C + (cr0 + m * 32 + q * 8) * (long)N + gc;
#pragma unroll
        for (int j = 0; j < 4; ++j)
          cp[(long)j * N] = acc[m][n][q * 4 + j] + bv[n];
      }
    }
  }
#undef PHASE
#undef STAGE_G
#undef GL
}

extern "C" void kernel_launch(void* const* d_in, const int* in_sizes, int n_in,
                              void* d_out, int out_size, void* d_ws, size_t ws_size,
                              hipStream_t stream)
{
  const float* x     = (const float*)d_in[0];
  const int*   wp    = (const int*)d_in[1];
  const float* scale = (const float*)d_in[2];
  const float* zp    = (const float*)d_in[3];
  const float* bias  = (const float*)d_in[4];
  float* out = (float*)d_out;

  bf16* Wb = (bf16*)d_ws;                                         // 33,554,432 B
  bf16* Xb = (bf16*)((char*)d_ws + (size_t)OUT_DIM * IN_DIM * 2); // 67,108,864 B

  dequant_w_kernel<<<(OUT_DIM * (long)IN_DIM / 8) / 256, 256, 0, stream>>>(wp, scale, zp, Wb);
  cvt_x_kernel<<<(M_DIM * (long)IN_DIM / 8) / 256, 256, 0, stream>>>(x, Xb);
  // grid = (8192/256)*(4096/256) = 32*16 = 512 blocks, 512 threads
  gemm_bt_bias_kernel<<<512, 512, 0, stream>>>(Xb, Wb, bias, out);
}